// Round 3
// baseline (997.707 us; speedup 1.0000x reference)
//
#include <hip/hip_runtime.h>

#define N_NODES 100000
#define N_EDGES 1600000
#define IN_CH 50
#define HID_CH 32
#define OUT_CH 16
#define EPSN 1e-12f

#define NPB 128                                  // nodes per bucket (dst>>7)
#define NBUCK ((N_NODES + NPB - 1) / NPB)        // 782
#define CAP 2560                                 // mean 2048, +11 sigma

// ---------------- layer-1 node transform: xl = x@W1l.T, self1 = x@W1r.T + b1l
__global__ __launch_bounds__(256) void k_xform1(
    const float* __restrict__ x, const float* __restrict__ W1l,
    const float* __restrict__ b1l, const float* __restrict__ W1r,
    float* __restrict__ xl, float* __restrict__ self1)
{
    int n = blockIdx.x * blockDim.x + threadIdx.x;
    if (n >= N_NODES) return;
    float row[IN_CH];
    #pragma unroll
    for (int k = 0; k < IN_CH; ++k) row[k] = x[(size_t)n * IN_CH + k];
    #pragma unroll 4
    for (int c = 0; c < HID_CH; ++c) {
        float aL = 0.f, aR = 0.f;
        #pragma unroll
        for (int k = 0; k < IN_CH; ++k) {
            aL = fmaf(row[k], W1l[c * IN_CH + k], aL);
            aR = fmaf(row[k], W1r[c * IN_CH + k], aR);
        }
        xl[(size_t)n * HID_CH + c] = aL;
        self1[(size_t)n * HID_CH + c] = aR + b1l[c];
    }
}

// ---------------- bin edges by dst range; packed (local<<24 | src)
__global__ __launch_bounds__(256) void k_bin(
    const int* __restrict__ src, const int* __restrict__ dst,
    int* __restrict__ bcnt, unsigned* __restrict__ bucket)
{
    int e = blockIdx.x * blockDim.x + threadIdx.x;
    if (e >= N_EDGES) return;
    int d = dst[e];
    int s = src[e];
    int b = d >> 7;
    int pos = atomicAdd(&bcnt[b], 1);
    if (pos < CAP)
        bucket[(size_t)b * CAP + pos] = ((unsigned)(d & (NPB - 1)) << 24) | (unsigned)s;
}

// ---------------- per-bucket LDS aggregation (layer 1) + finalize + fused xform2
__global__ __launch_bounds__(512) void k_aggr1_x2(
    const int* __restrict__ bcnt, const unsigned* __restrict__ bucket,
    const float* __restrict__ xl, const float* __restrict__ self1,
    const float* __restrict__ W2l, const float* __restrict__ b2l,
    const float* __restrict__ W2r,
    float* __restrict__ hl, float* __restrict__ hself, float* __restrict__ degf)
{
    __shared__ float tile[NPB * 33];   // [128][32 ch + deg], stride 33 = no bank conflicts
    int tid = threadIdx.x;
    int b = blockIdx.x;
    for (int i = tid; i < NPB * 33; i += 512) tile[i] = 0.f;
    __syncthreads();

    int cnt = min(bcnt[b], CAP);
    const unsigned* bp = bucket + (size_t)b * CAP;
    int g = tid >> 3;          // 64 groups of 8 lanes
    int q = tid & 7;
    int i = g;
    for (; i + 64 < cnt; i += 128) {   // 2-way unroll: two gathers in flight
        unsigned p0 = bp[i];
        unsigned p1 = bp[i + 64];
        int s0 = p0 & 0xFFFFFF, l0 = p0 >> 24;
        int s1 = p1 & 0xFFFFFF, l1 = p1 >> 24;
        float4 v0 = *reinterpret_cast<const float4*>(xl + (size_t)s0 * HID_CH + q * 4);
        float4 v1 = *reinterpret_cast<const float4*>(xl + (size_t)s1 * HID_CH + q * 4);
        float* t0 = tile + l0 * 33 + q * 4;
        atomicAdd(t0 + 0, v0.x); atomicAdd(t0 + 1, v0.y);
        atomicAdd(t0 + 2, v0.z); atomicAdd(t0 + 3, v0.w);
        float* t1 = tile + l1 * 33 + q * 4;
        atomicAdd(t1 + 0, v1.x); atomicAdd(t1 + 1, v1.y);
        atomicAdd(t1 + 2, v1.z); atomicAdd(t1 + 3, v1.w);
        if (q == 0) {
            atomicAdd(&tile[l0 * 33 + 32], 1.0f);
            atomicAdd(&tile[l1 * 33 + 32], 1.0f);
        }
    }
    for (; i < cnt; i += 64) {
        unsigned p0 = bp[i];
        int s0 = p0 & 0xFFFFFF, l0 = p0 >> 24;
        float4 v0 = *reinterpret_cast<const float4*>(xl + (size_t)s0 * HID_CH + q * 4);
        float* t0 = tile + l0 * 33 + q * 4;
        atomicAdd(t0 + 0, v0.x); atomicAdd(t0 + 1, v0.y);
        atomicAdd(t0 + 2, v0.z); atomicAdd(t0 + 3, v0.w);
        if (q == 0) atomicAdd(&tile[l0 * 33 + 32], 1.0f);
    }
    __syncthreads();

    // finalize: mean + self + L2norm + relu; h written back into tile
    int lt = tid & 15, ln = tid >> 4;    // 16 lanes per node, 2 ch per lane
    for (int loc = ln; loc < NPB; loc += 32) {
        int n = b * NPB + loc;
        if (n >= N_NODES) break;
        float dgf = tile[loc * 33 + 32];
        float invd = 1.0f / fmaxf(dgf, 1.0f);
        float a0 = tile[loc * 33 + lt * 2];
        float a1 = tile[loc * 33 + lt * 2 + 1];
        float2 sf = *reinterpret_cast<const float2*>(self1 + (size_t)n * HID_CH + lt * 2);
        float h0 = fmaf(a0, invd, sf.x);
        float h1 = fmaf(a1, invd, sf.y);
        float ss = h0 * h0 + h1 * h1;
        ss += __shfl_xor(ss, 1);
        ss += __shfl_xor(ss, 2);
        ss += __shfl_xor(ss, 4);
        ss += __shfl_xor(ss, 8);
        float sc = 1.0f / fmaxf(sqrtf(ss), EPSN);
        tile[loc * 33 + lt * 2]     = fmaxf(h0 * sc, 0.f);
        tile[loc * 33 + lt * 2 + 1] = fmaxf(h1 * sc, 0.f);
        if (lt == 0) degf[n] = dgf;
    }
    __syncthreads();

    // fused layer-2 transform from LDS h: hl = h@W2l.T, hself = h@W2r.T + b2l
    for (int loc = ln; loc < NPB; loc += 32) {
        int n = b * NPB + loc;
        if (n >= N_NODES) break;
        const float* hrow = tile + loc * 33;
        float aL = 0.f, aR = 0.f;
        #pragma unroll
        for (int k = 0; k < HID_CH; ++k) {
            float hv = hrow[k];
            aL = fmaf(hv, W2l[lt * HID_CH + k], aL);
            aR = fmaf(hv, W2r[lt * HID_CH + k], aR);
        }
        hl[(size_t)n * OUT_CH + lt] = aL;
        hself[(size_t)n * OUT_CH + lt] = aR + b2l[lt];
    }
}

// ---------------- per-bucket LDS aggregation (layer 2) + norm + log_softmax
__global__ __launch_bounds__(512) void k_aggr2_fin(
    const int* __restrict__ bcnt, const unsigned* __restrict__ bucket,
    const float* __restrict__ hl, const float* __restrict__ hself,
    const float* __restrict__ degf, float* __restrict__ out)
{
    __shared__ float tile[NPB * 17];   // [128][16 ch], stride 17
    int tid = threadIdx.x;
    int b = blockIdx.x;
    for (int i = tid; i < NPB * 17; i += 512) tile[i] = 0.f;
    __syncthreads();

    int cnt = min(bcnt[b], CAP);
    const unsigned* bp = bucket + (size_t)b * CAP;
    int g = tid >> 2;          // 128 groups of 4 lanes
    int q = tid & 3;
    int i = g;
    for (; i + 128 < cnt; i += 256) {
        unsigned p0 = bp[i];
        unsigned p1 = bp[i + 128];
        int s0 = p0 & 0xFFFFFF, l0 = p0 >> 24;
        int s1 = p1 & 0xFFFFFF, l1 = p1 >> 24;
        float4 v0 = *reinterpret_cast<const float4*>(hl + (size_t)s0 * OUT_CH + q * 4);
        float4 v1 = *reinterpret_cast<const float4*>(hl + (size_t)s1 * OUT_CH + q * 4);
        float* t0 = tile + l0 * 17 + q * 4;
        atomicAdd(t0 + 0, v0.x); atomicAdd(t0 + 1, v0.y);
        atomicAdd(t0 + 2, v0.z); atomicAdd(t0 + 3, v0.w);
        float* t1 = tile + l1 * 17 + q * 4;
        atomicAdd(t1 + 0, v1.x); atomicAdd(t1 + 1, v1.y);
        atomicAdd(t1 + 2, v1.z); atomicAdd(t1 + 3, v1.w);
    }
    for (; i < cnt; i += 128) {
        unsigned p0 = bp[i];
        int s0 = p0 & 0xFFFFFF, l0 = p0 >> 24;
        float4 v0 = *reinterpret_cast<const float4*>(hl + (size_t)s0 * OUT_CH + q * 4);
        float* t0 = tile + l0 * 17 + q * 4;
        atomicAdd(t0 + 0, v0.x); atomicAdd(t0 + 1, v0.y);
        atomicAdd(t0 + 2, v0.z); atomicAdd(t0 + 3, v0.w);
    }
    __syncthreads();

    int lt = tid & 15, ln = tid >> 4;   // 16 lanes per node, 1 ch per lane
    for (int loc = ln; loc < NPB; loc += 32) {
        int n = b * NPB + loc;
        if (n >= N_NODES) break;
        float invd = 1.0f / fmaxf(degf[n], 1.0f);
        float v = fmaf(tile[loc * 17 + lt], invd, hself[(size_t)n * OUT_CH + lt]);
        float ss = v * v;
        ss += __shfl_xor(ss, 1);
        ss += __shfl_xor(ss, 2);
        ss += __shfl_xor(ss, 4);
        ss += __shfl_xor(ss, 8);
        v *= 1.0f / fmaxf(sqrtf(ss), EPSN);
        float m = v;
        m = fmaxf(m, __shfl_xor(m, 1));
        m = fmaxf(m, __shfl_xor(m, 2));
        m = fmaxf(m, __shfl_xor(m, 4));
        m = fmaxf(m, __shfl_xor(m, 8));
        float ex = expf(v - m);
        float sum = ex;
        sum += __shfl_xor(sum, 1);
        sum += __shfl_xor(sum, 2);
        sum += __shfl_xor(sum, 4);
        sum += __shfl_xor(sum, 8);
        out[(size_t)n * OUT_CH + lt] = (v - m) - logf(sum);
    }
}

extern "C" void kernel_launch(void* const* d_in, const int* in_sizes, int n_in,
                              void* d_out, int out_size, void* d_ws, size_t ws_size,
                              hipStream_t stream) {
    const float* x   = (const float*)d_in[0];
    const int*   ei  = (const int*)d_in[1];   // [2, E] int32
    const float* W1l = (const float*)d_in[2];
    const float* b1l = (const float*)d_in[3];
    const float* W1r = (const float*)d_in[4];
    const float* W2l = (const float*)d_in[5];
    const float* b2l = (const float*)d_in[6];
    const float* W2r = (const float*)d_in[7];
    float* out = (float*)d_out;

    const int* src = ei;
    const int* dst = ei + N_EDGES;

    // workspace layout (~47 MB)
    char* p = (char*)d_ws;
    float*    xl     = (float*)p;    p += (size_t)N_NODES * HID_CH * 4;   // 12.8 MB
    float*    self1  = (float*)p;    p += (size_t)N_NODES * HID_CH * 4;   // 12.8 MB
    float*    hl     = (float*)p;    p += (size_t)N_NODES * OUT_CH * 4;   //  6.4 MB
    float*    hself  = (float*)p;    p += (size_t)N_NODES * OUT_CH * 4;   //  6.4 MB
    float*    degf   = (float*)p;    p += (size_t)N_NODES * 4;            //  0.4 MB
    int*      bcnt   = (int*)p;      p += (size_t)NBUCK * 4;
    unsigned* bucket = (unsigned*)p; p += (size_t)NBUCK * CAP * 4;        //  8.0 MB

    hipMemsetAsync(bcnt, 0, (size_t)NBUCK * 4, stream);

    k_xform1<<<(N_NODES + 255) / 256, 256, 0, stream>>>(x, W1l, b1l, W1r, xl, self1);
    k_bin<<<(N_EDGES + 255) / 256, 256, 0, stream>>>(src, dst, bcnt, bucket);
    k_aggr1_x2<<<NBUCK, 512, 0, stream>>>(bcnt, bucket, xl, self1,
                                          W2l, b2l, W2r, hl, hself, degf);
    k_aggr2_fin<<<NBUCK, 512, 0, stream>>>(bcnt, bucket, hl, hself, degf, out);
}

// Round 4
// 209.870 us; speedup vs baseline: 4.7539x; 4.7539x over previous
//
#include <hip/hip_runtime.h>

#define N_NODES 100000
#define N_EDGES 1600000
#define IN_CH 50
#define HID_CH 32
#define OUT_CH 16
#define EPSN 1e-12f

#define NPB 128                                  // nodes per bucket (dst>>7)
#define NBUCK ((N_NODES + NPB - 1) / NPB)        // 782
#define EPB 8192                                 // edges per count/place block
#define CBLK ((N_EDGES + EPB - 1) / EPB)         // 196
#define LCAP 2816                                // LDS bucket capacity (mean 2048, +17 sigma)

// ---------------- layer-1 node transform: xl = x@W1l.T, self1 = x@W1r.T + b1l
__global__ __launch_bounds__(256) void k_xform1(
    const float* __restrict__ x, const float* __restrict__ W1l,
    const float* __restrict__ b1l, const float* __restrict__ W1r,
    float* __restrict__ xl, float* __restrict__ self1)
{
    int n = blockIdx.x * blockDim.x + threadIdx.x;
    if (n >= N_NODES) return;
    float row[IN_CH];
    #pragma unroll
    for (int k = 0; k < IN_CH; ++k) row[k] = x[(size_t)n * IN_CH + k];
    #pragma unroll 4
    for (int c = 0; c < HID_CH; ++c) {
        float aL = 0.f, aR = 0.f;
        #pragma unroll
        for (int k = 0; k < IN_CH; ++k) {
            aL = fmaf(row[k], W1l[c * IN_CH + k], aL);
            aR = fmaf(row[k], W1r[c * IN_CH + k], aR);
        }
        xl[(size_t)n * HID_CH + c] = aL;
        self1[(size_t)n * HID_CH + c] = aR + b1l[c];
    }
}

// ---------------- per-block privatized bucket histogram (no global atomics)
__global__ __launch_bounds__(256) void k_count(
    const int* __restrict__ dst, int* __restrict__ cnt)
{
    __shared__ int hist[NBUCK];
    int tid = threadIdx.x;
    for (int i = tid; i < NBUCK; i += 256) hist[i] = 0;
    __syncthreads();
    int base = blockIdx.x * EPB;
    for (int i = tid; i < EPB; i += 256) {
        int e = base + i;
        if (e < N_EDGES) atomicAdd(&hist[dst[e] >> 7], 1);
    }
    __syncthreads();
    for (int b = tid; b < NBUCK; b += 256) cnt[b * CBLK + blockIdx.x] = hist[b];
}

// ---------------- scan each bucket's per-block counts (one wave per bucket)
__global__ __launch_bounds__(64) void k_scanA(
    int* __restrict__ cnt, int* __restrict__ tot)
{
    int b = blockIdx.x, lane = threadIdx.x;
    int carry = 0;
    for (int c = 0; c < CBLK; c += 64) {
        int idx = c + lane;
        int v = (idx < CBLK) ? cnt[b * CBLK + idx] : 0;
        int s = v;
        #pragma unroll
        for (int off = 1; off < 64; off <<= 1) {
            int t = __shfl_up(s, off);
            if (lane >= off) s += t;
        }
        if (idx < CBLK) cnt[b * CBLK + idx] = carry + s - v;  // exclusive within bucket
        carry += __shfl(s, 63);
    }
    if (lane == 0) tot[b] = carry;
}

// ---------------- scan bucket totals (single block)
__global__ __launch_bounds__(1024) void k_scanB(
    const int* __restrict__ tot, int* __restrict__ bbase)
{
    __shared__ int buf[1024];
    int tid = threadIdx.x;
    int v = (tid < NBUCK) ? tot[tid] : 0;
    buf[tid] = v;
    __syncthreads();
    for (int off = 1; off < 1024; off <<= 1) {
        int t = (tid >= off) ? buf[tid - off] : 0;
        __syncthreads();
        buf[tid] += t;
        __syncthreads();
    }
    if (tid < NBUCK) bbase[tid] = buf[tid] - v;
    if (tid == NBUCK - 1) bbase[NBUCK] = buf[tid];
}

// ---------------- place edges at exact packed positions (LDS rank only)
__global__ __launch_bounds__(256) void k_place(
    const int* __restrict__ src, const int* __restrict__ dst,
    const int* __restrict__ cnt, const int* __restrict__ bbase,
    unsigned* __restrict__ ebuf)
{
    __shared__ int hbase[NBUCK];
    __shared__ int hrank[NBUCK];
    int tid = threadIdx.x;
    for (int b = tid; b < NBUCK; b += 256) {
        hbase[b] = bbase[b] + cnt[b * CBLK + blockIdx.x];
        hrank[b] = 0;
    }
    __syncthreads();
    int base = blockIdx.x * EPB;
    for (int i = tid; i < EPB; i += 256) {
        int e = base + i;
        if (e < N_EDGES) {
            int d = dst[e];
            int bb = d >> 7;
            int r = atomicAdd(&hrank[bb], 1);
            ebuf[hbase[bb] + r] = ((unsigned)(d & (NPB - 1)) << 24) | (unsigned)src[e];
        }
    }
}

// ---------------- per-bucket: LDS counting-sort by node, register gather-sum,
//                  finalize layer 1, fused layer-2 transform via shfl
__global__ __launch_bounds__(512) void k_aggr1_x2(
    const int* __restrict__ bbase, const unsigned* __restrict__ ebuf,
    const float* __restrict__ xl, const float* __restrict__ self1,
    const float* __restrict__ W2l, const float* __restrict__ b2l,
    const float* __restrict__ W2r,
    float* __restrict__ hl, float* __restrict__ hself,
    int* __restrict__ gsorted, int2* __restrict__ gmeta)
{
    __shared__ unsigned ent[LCAP];
    __shared__ int slist[LCAP];
    __shared__ int hcnt[NPB];
    __shared__ int hoff[NPB + 1];
    __shared__ float w2[2 * OUT_CH * 33];   // stride 33: conflict-free by-lane reads
    __shared__ float b2s[OUT_CH];

    int tid = threadIdx.x;
    int b = blockIdx.x;
    for (int i = tid; i < OUT_CH * HID_CH; i += 512) {
        int o = i >> 5, k = i & 31;
        w2[o * 33 + k] = W2l[i];
        w2[(OUT_CH + o) * 33 + k] = W2r[i];
    }
    if (tid < OUT_CH) b2s[tid] = b2l[tid];
    if (tid < NPB) hcnt[tid] = 0;
    __syncthreads();

    int beg = bbase[b];
    int cnt = min(bbase[b + 1] - beg, LCAP);
    for (int i = tid; i < cnt; i += 512) {
        unsigned e = ebuf[beg + i];
        ent[i] = e;
        atomicAdd(&hcnt[e >> 24], 1);
    }
    __syncthreads();
    if (tid < 64) {   // scan 128 node counts in one wave
        int v0 = hcnt[2 * tid], v1 = hcnt[2 * tid + 1];
        int s = v0 + v1;
        #pragma unroll
        for (int off = 1; off < 64; off <<= 1) {
            int t = __shfl_up(s, off);
            if (tid >= off) s += t;
        }
        int exc = s - v0 - v1;
        hoff[2 * tid] = exc;
        hoff[2 * tid + 1] = exc + v0;
        if (tid == 63) hoff[NPB] = s;
    }
    __syncthreads();
    if (tid < NPB) hcnt[tid] = 0;
    __syncthreads();
    for (int i = tid; i < cnt; i += 512) {
        unsigned e = ent[i];
        int loc = e >> 24;
        int r = atomicAdd(&hcnt[loc], 1);
        slist[hoff[loc] + r] = (int)(e & 0xFFFFFFu);
    }
    __syncthreads();
    // node-sorted adjacency back to global (coalesced) for layer 2
    for (int i = tid; i < cnt; i += 512) gsorted[beg + i] = slist[i];

    int lt = tid & 15, grp = tid >> 4, wl = tid & 63;
    for (int pass = 0; pass < 4; ++pass) {
        int loc = pass * 32 + grp;
        int n = b * NPB + loc;
        if (n >= N_NODES) continue;
        int s0 = hoff[loc];
        int dg = hoff[loc + 1] - s0;
        float a0 = 0.f, a1 = 0.f, c0 = 0.f, c1 = 0.f;
        int i = 0;
        for (; i + 1 < dg; i += 2) {
            int sA = slist[s0 + i];
            int sB = slist[s0 + i + 1];
            float2 vA = *reinterpret_cast<const float2*>(xl + (size_t)sA * HID_CH + lt * 2);
            float2 vB = *reinterpret_cast<const float2*>(xl + (size_t)sB * HID_CH + lt * 2);
            a0 += vA.x; a1 += vA.y; c0 += vB.x; c1 += vB.y;
        }
        if (i < dg) {
            int sA = slist[s0 + i];
            float2 vA = *reinterpret_cast<const float2*>(xl + (size_t)sA * HID_CH + lt * 2);
            a0 += vA.x; a1 += vA.y;
        }
        float invd = 1.0f / (float)max(dg, 1);
        float2 sf = *reinterpret_cast<const float2*>(self1 + (size_t)n * HID_CH + lt * 2);
        float h0 = fmaf(a0 + c0, invd, sf.x);
        float h1 = fmaf(a1 + c1, invd, sf.y);
        float ss = h0 * h0 + h1 * h1;
        ss += __shfl_xor(ss, 1);
        ss += __shfl_xor(ss, 2);
        ss += __shfl_xor(ss, 4);
        ss += __shfl_xor(ss, 8);
        float sc = 1.0f / fmaxf(sqrtf(ss), EPSN);
        h0 = fmaxf(h0 * sc, 0.f);   // h channel lt*2
        h1 = fmaxf(h1 * sc, 0.f);   // h channel lt*2+1
        // fused xform2: lane lt computes output channel lt from all 32 h via shfl
        float aL = 0.f, aR = 0.f;
        #pragma unroll
        for (int k = 0; k < HID_CH; ++k) {
            int srcl = (wl & 48) | (k >> 1);
            float hv = (k & 1) ? __shfl(h1, srcl) : __shfl(h0, srcl);
            aL = fmaf(hv, w2[lt * 33 + k], aL);
            aR = fmaf(hv, w2[(OUT_CH + lt) * 33 + k], aR);
        }
        hl[(size_t)n * OUT_CH + lt] = aL;
        hself[(size_t)n * OUT_CH + lt] = aR + b2s[lt];
        if (lt == 0) gmeta[n] = make_int2(beg + s0, dg);
    }
}

// ---------------- layer-2 gather + mean + self + L2norm + log_softmax
__global__ __launch_bounds__(256) void k_aggr2_fin(
    const int2* __restrict__ gmeta, const int* __restrict__ gsorted,
    const float* __restrict__ hl, const float* __restrict__ hself,
    float* __restrict__ out)
{
    int gid = blockIdx.x * blockDim.x + threadIdx.x;
    int n = gid >> 4, t = gid & 15;
    if (n >= N_NODES) return;
    int2 md = gmeta[n];
    int beg = md.x, dg = md.y;
    float a0 = 0.f, a1 = 0.f;
    int i = 0;
    for (; i + 1 < dg; i += 2) {
        int sA = gsorted[beg + i];
        int sB = gsorted[beg + i + 1];
        a0 += hl[(size_t)sA * OUT_CH + t];
        a1 += hl[(size_t)sB * OUT_CH + t];
    }
    if (i < dg) a0 += hl[(size_t)gsorted[beg + i] * OUT_CH + t];
    float invd = 1.0f / (float)max(dg, 1);
    float v = fmaf(a0 + a1, invd, hself[(size_t)n * OUT_CH + t]);
    float ss = v * v;
    ss += __shfl_xor(ss, 1);
    ss += __shfl_xor(ss, 2);
    ss += __shfl_xor(ss, 4);
    ss += __shfl_xor(ss, 8);
    v *= 1.0f / fmaxf(sqrtf(ss), EPSN);
    float m = v;
    m = fmaxf(m, __shfl_xor(m, 1));
    m = fmaxf(m, __shfl_xor(m, 2));
    m = fmaxf(m, __shfl_xor(m, 4));
    m = fmaxf(m, __shfl_xor(m, 8));
    float ex = expf(v - m);
    float sum = ex;
    sum += __shfl_xor(sum, 1);
    sum += __shfl_xor(sum, 2);
    sum += __shfl_xor(sum, 4);
    sum += __shfl_xor(sum, 8);
    out[(size_t)n * OUT_CH + t] = (v - m) - logf(sum);
}

extern "C" void kernel_launch(void* const* d_in, const int* in_sizes, int n_in,
                              void* d_out, int out_size, void* d_ws, size_t ws_size,
                              hipStream_t stream) {
    const float* x   = (const float*)d_in[0];
    const int*   ei  = (const int*)d_in[1];   // [2, E] int32
    const float* W1l = (const float*)d_in[2];
    const float* b1l = (const float*)d_in[3];
    const float* W1r = (const float*)d_in[4];
    const float* W2l = (const float*)d_in[5];
    const float* b2l = (const float*)d_in[6];
    const float* W2r = (const float*)d_in[7];
    float* out = (float*)d_out;

    const int* src = ei;
    const int* dst = ei + N_EDGES;

    // workspace layout (~53 MB)
    char* p = (char*)d_ws;
    float*    xl      = (float*)p;    p += (size_t)N_NODES * HID_CH * 4;   // 12.8 MB
    float*    self1   = (float*)p;    p += (size_t)N_NODES * HID_CH * 4;   // 12.8 MB
    float*    hl      = (float*)p;    p += (size_t)N_NODES * OUT_CH * 4;   //  6.4 MB
    float*    hself   = (float*)p;    p += (size_t)N_NODES * OUT_CH * 4;   //  6.4 MB
    int2*     gmeta   = (int2*)p;     p += (size_t)N_NODES * 8;            //  0.8 MB
    int*      cnt     = (int*)p;      p += (size_t)NBUCK * CBLK * 4;       //  0.6 MB
    int*      tot     = (int*)p;      p += (size_t)NBUCK * 4;
    int*      bbase   = (int*)p;      p += (size_t)(NBUCK + 1) * 4;
    unsigned* ebuf    = (unsigned*)p; p += (size_t)N_EDGES * 4;            //  6.4 MB
    int*      gsorted = (int*)p;      p += (size_t)N_EDGES * 4;            //  6.4 MB

    k_xform1<<<(N_NODES + 255) / 256, 256, 0, stream>>>(x, W1l, b1l, W1r, xl, self1);
    k_count<<<CBLK, 256, 0, stream>>>(dst, cnt);
    k_scanA<<<NBUCK, 64, 0, stream>>>(cnt, tot);
    k_scanB<<<1, 1024, 0, stream>>>(tot, bbase);
    k_place<<<CBLK, 256, 0, stream>>>(src, dst, cnt, bbase, ebuf);
    k_aggr1_x2<<<NBUCK, 512, 0, stream>>>(bbase, ebuf, xl, self1,
                                          W2l, b2l, W2r, hl, hself, gsorted, gmeta);
    k_aggr2_fin<<<(N_NODES * 16 + 255) / 256, 256, 0, stream>>>(gmeta, gsorted,
                                                                hl, hself, out);
}

// Round 5
// 168.953 us; speedup vs baseline: 5.9052x; 1.2422x over previous
//
#include <hip/hip_runtime.h>

#define N_NODES 100000
#define N_EDGES 1600000
#define IN_CH 50
#define HID_CH 32
#define OUT_CH 16
#define EPSN 1e-12f

#define NPB 128                                  // nodes per bucket (dst>>7)
#define NBUCK ((N_NODES + NPB - 1) / NPB)        // 782
#define EPB 8192                                 // edges per count/place block
#define CBLK ((N_EDGES + EPB - 1) / EPB)         // 196
#define LCAP 2816                                // LDS bucket capacity (mean 2048, +17 sigma)

#define KPAD 52                                  // 50 padded to multiple of 4
#define KV (KPAD / 4)                            // 13 float4 per row
#define TNB 128                                  // nodes per xform1 block

// ---------------- layer-1 transform as LDS-tiled GEMM: [N x 50] @ [50 x 64]
// outputs: cols 0..31 -> xl (W1l), cols 32..63 -> self1 (W1r + b1l)
// thread (q = tid&7, loc = tid>>3): 4 nodes {loc+32nn} x 8 outputs {j*8+q}
__global__ __launch_bounds__(256) void k_xform1(
    const float* __restrict__ x, const float* __restrict__ W1l,
    const float* __restrict__ b1l, const float* __restrict__ W1r,
    float* __restrict__ xl, float* __restrict__ self1)
{
    __shared__ float xs[TNB * KPAD];    // 26624 B
    __shared__ float wt[64 * KPAD];     // 13312 B
    __shared__ float bsh[32];
    int tid = threadIdx.x;
    int base = blockIdx.x * TNB;

    // stage x tile (coalesced); rows past N_NODES read as 0
    for (int i = tid; i < TNB * IN_CH; i += 256) {
        int r = i / IN_CH, k = i - r * IN_CH;
        int n = base + r;
        xs[r * KPAD + k] = (n < N_NODES) ? x[(size_t)base * IN_CH + i] : 0.f;
    }
    // K pads
    xs[(tid >> 1) * KPAD + IN_CH + (tid & 1)] = 0.f;            // 256 = 128*2
    if (tid < 128) wt[(tid >> 1) * KPAD + IN_CH + (tid & 1)] = 0.f;
    // stage weights: rows 0..31 = W1l, 32..63 = W1r
    for (int i = tid; i < 64 * IN_CH; i += 256) {
        int o = i / IN_CH, k = i - o * IN_CH;
        wt[o * KPAD + k] = (o < 32) ? W1l[i] : W1r[i - 32 * IN_CH];
    }
    if (tid < 32) bsh[tid] = b1l[tid];
    __syncthreads();

    int q = tid & 7;
    int loc = tid >> 3;
    const float4* xs4 = (const float4*)xs;
    const float4* wt4 = (const float4*)wt;
    float acc[4][8] = {};
    for (int kk = 0; kk < KV; ++kk) {
        float4 w[8];
        #pragma unroll
        for (int j = 0; j < 8; ++j) w[j] = wt4[(j * 8 + q) * KV + kk];
        #pragma unroll
        for (int nn = 0; nn < 4; ++nn) {
            float4 xv = xs4[(loc + nn * 32) * KV + kk];
            #pragma unroll
            for (int j = 0; j < 8; ++j) {
                acc[nn][j] = fmaf(xv.x, w[j].x, acc[nn][j]);
                acc[nn][j] = fmaf(xv.y, w[j].y, acc[nn][j]);
                acc[nn][j] = fmaf(xv.z, w[j].z, acc[nn][j]);
                acc[nn][j] = fmaf(xv.w, w[j].w, acc[nn][j]);
            }
        }
    }
    #pragma unroll
    for (int nn = 0; nn < 4; ++nn) {
        int n = base + loc + nn * 32;
        if (n < N_NODES) {
            #pragma unroll
            for (int j = 0; j < 8; ++j) {
                if (j < 4)
                    xl[(size_t)n * HID_CH + j * 8 + q] = acc[nn][j];
                else
                    self1[(size_t)n * HID_CH + (j - 4) * 8 + q] =
                        acc[nn][j] + bsh[(j - 4) * 8 + q];
            }
        }
    }
}

// ---------------- per-block privatized bucket histogram (no global atomics)
__global__ __launch_bounds__(256) void k_count(
    const int* __restrict__ dst, int* __restrict__ cnt)
{
    __shared__ int hist[NBUCK];
    int tid = threadIdx.x;
    for (int i = tid; i < NBUCK; i += 256) hist[i] = 0;
    __syncthreads();
    int base = blockIdx.x * EPB;
    for (int i = tid; i < EPB; i += 256) {
        int e = base + i;
        if (e < N_EDGES) atomicAdd(&hist[dst[e] >> 7], 1);
    }
    __syncthreads();
    for (int b = tid; b < NBUCK; b += 256) cnt[b * CBLK + blockIdx.x] = hist[b];
}

// ---------------- scan each bucket's per-block counts (one wave per bucket)
__global__ __launch_bounds__(64) void k_scanA(
    int* __restrict__ cnt, int* __restrict__ tot)
{
    int b = blockIdx.x, lane = threadIdx.x;
    int carry = 0;
    for (int c = 0; c < CBLK; c += 64) {
        int idx = c + lane;
        int v = (idx < CBLK) ? cnt[b * CBLK + idx] : 0;
        int s = v;
        #pragma unroll
        for (int off = 1; off < 64; off <<= 1) {
            int t = __shfl_up(s, off);
            if (lane >= off) s += t;
        }
        if (idx < CBLK) cnt[b * CBLK + idx] = carry + s - v;  // exclusive within bucket
        carry += __shfl(s, 63);
    }
    if (lane == 0) tot[b] = carry;
}

// ---------------- scan bucket totals (single block)
__global__ __launch_bounds__(1024) void k_scanB(
    const int* __restrict__ tot, int* __restrict__ bbase)
{
    __shared__ int buf[1024];
    int tid = threadIdx.x;
    int v = (tid < NBUCK) ? tot[tid] : 0;
    buf[tid] = v;
    __syncthreads();
    for (int off = 1; off < 1024; off <<= 1) {
        int t = (tid >= off) ? buf[tid - off] : 0;
        __syncthreads();
        buf[tid] += t;
        __syncthreads();
    }
    if (tid < NBUCK) bbase[tid] = buf[tid] - v;
    if (tid == NBUCK - 1) bbase[NBUCK] = buf[tid];
}

// ---------------- place edges at exact packed positions (LDS rank only)
__global__ __launch_bounds__(256) void k_place(
    const int* __restrict__ src, const int* __restrict__ dst,
    const int* __restrict__ cnt, const int* __restrict__ bbase,
    unsigned* __restrict__ ebuf)
{
    __shared__ int hbase[NBUCK];
    __shared__ int hrank[NBUCK];
    int tid = threadIdx.x;
    for (int b = tid; b < NBUCK; b += 256) {
        hbase[b] = bbase[b] + cnt[b * CBLK + blockIdx.x];
        hrank[b] = 0;
    }
    __syncthreads();
    int base = blockIdx.x * EPB;
    for (int i = tid; i < EPB; i += 256) {
        int e = base + i;
        if (e < N_EDGES) {
            int d = dst[e];
            int bb = d >> 7;
            int r = atomicAdd(&hrank[bb], 1);
            ebuf[hbase[bb] + r] = ((unsigned)(d & (NPB - 1)) << 24) | (unsigned)src[e];
        }
    }
}

// ---------------- per-bucket: LDS counting-sort by node, register gather-sum,
//                  finalize layer 1, fused layer-2 transform via shfl
__global__ __launch_bounds__(512) void k_aggr1_x2(
    const int* __restrict__ bbase, const unsigned* __restrict__ ebuf,
    const float* __restrict__ xl, const float* __restrict__ self1,
    const float* __restrict__ W2l, const float* __restrict__ b2l,
    const float* __restrict__ W2r,
    float* __restrict__ hl, float* __restrict__ hself,
    int* __restrict__ gsorted, int2* __restrict__ gmeta)
{
    __shared__ unsigned ent[LCAP];
    __shared__ int slist[LCAP];
    __shared__ int hcnt[NPB];
    __shared__ int hoff[NPB + 1];
    __shared__ float w2[2 * OUT_CH * 33];   // stride 33: conflict-free by-lane reads
    __shared__ float b2s[OUT_CH];

    int tid = threadIdx.x;
    int b = blockIdx.x;
    for (int i = tid; i < OUT_CH * HID_CH; i += 512) {
        int o = i >> 5, k = i & 31;
        w2[o * 33 + k] = W2l[i];
        w2[(OUT_CH + o) * 33 + k] = W2r[i];
    }
    if (tid < OUT_CH) b2s[tid] = b2l[tid];
    if (tid < NPB) hcnt[tid] = 0;
    __syncthreads();

    int beg = bbase[b];
    int cnt = min(bbase[b + 1] - beg, LCAP);
    for (int i = tid; i < cnt; i += 512) {
        unsigned e = ebuf[beg + i];
        ent[i] = e;
        atomicAdd(&hcnt[e >> 24], 1);
    }
    __syncthreads();
    if (tid < 64) {   // scan 128 node counts in one wave
        int v0 = hcnt[2 * tid], v1 = hcnt[2 * tid + 1];
        int s = v0 + v1;
        #pragma unroll
        for (int off = 1; off < 64; off <<= 1) {
            int t = __shfl_up(s, off);
            if (tid >= off) s += t;
        }
        int exc = s - v0 - v1;
        hoff[2 * tid] = exc;
        hoff[2 * tid + 1] = exc + v0;
        if (tid == 63) hoff[NPB] = s;
    }
    __syncthreads();
    if (tid < NPB) hcnt[tid] = 0;
    __syncthreads();
    for (int i = tid; i < cnt; i += 512) {
        unsigned e = ent[i];
        int loc = e >> 24;
        int r = atomicAdd(&hcnt[loc], 1);
        slist[hoff[loc] + r] = (int)(e & 0xFFFFFFu);
    }
    __syncthreads();
    // node-sorted adjacency back to global (coalesced) for layer 2
    for (int i = tid; i < cnt; i += 512) gsorted[beg + i] = slist[i];

    int lt = tid & 15, grp = tid >> 4, wl = tid & 63;
    for (int pass = 0; pass < 4; ++pass) {
        int loc = pass * 32 + grp;
        int n = b * NPB + loc;
        if (n >= N_NODES) continue;
        int s0 = hoff[loc];
        int dg = hoff[loc + 1] - s0;
        float a0 = 0.f, a1 = 0.f, c0 = 0.f, c1 = 0.f;
        int i = 0;
        for (; i + 1 < dg; i += 2) {
            int sA = slist[s0 + i];
            int sB = slist[s0 + i + 1];
            float2 vA = *reinterpret_cast<const float2*>(xl + (size_t)sA * HID_CH + lt * 2);
            float2 vB = *reinterpret_cast<const float2*>(xl + (size_t)sB * HID_CH + lt * 2);
            a0 += vA.x; a1 += vA.y; c0 += vB.x; c1 += vB.y;
        }
        if (i < dg) {
            int sA = slist[s0 + i];
            float2 vA = *reinterpret_cast<const float2*>(xl + (size_t)sA * HID_CH + lt * 2);
            a0 += vA.x; a1 += vA.y;
        }
        float invd = 1.0f / (float)max(dg, 1);
        float2 sf = *reinterpret_cast<const float2*>(self1 + (size_t)n * HID_CH + lt * 2);
        float h0 = fmaf(a0 + c0, invd, sf.x);
        float h1 = fmaf(a1 + c1, invd, sf.y);
        float ss = h0 * h0 + h1 * h1;
        ss += __shfl_xor(ss, 1);
        ss += __shfl_xor(ss, 2);
        ss += __shfl_xor(ss, 4);
        ss += __shfl_xor(ss, 8);
        float sc = 1.0f / fmaxf(sqrtf(ss), EPSN);
        h0 = fmaxf(h0 * sc, 0.f);   // h channel lt*2
        h1 = fmaxf(h1 * sc, 0.f);   // h channel lt*2+1
        // fused xform2: lane lt computes output channel lt from all 32 h via shfl
        float aL = 0.f, aR = 0.f;
        #pragma unroll
        for (int k = 0; k < HID_CH; ++k) {
            int srcl = (wl & 48) | (k >> 1);
            float hv = (k & 1) ? __shfl(h1, srcl) : __shfl(h0, srcl);
            aL = fmaf(hv, w2[lt * 33 + k], aL);
            aR = fmaf(hv, w2[(OUT_CH + lt) * 33 + k], aR);
        }
        hl[(size_t)n * OUT_CH + lt] = aL;
        hself[(size_t)n * OUT_CH + lt] = aR + b2s[lt];
        if (lt == 0) gmeta[n] = make_int2(beg + s0, dg);
    }
}

// ---------------- layer-2 gather + mean + self + L2norm + log_softmax
__global__ __launch_bounds__(256) void k_aggr2_fin(
    const int2* __restrict__ gmeta, const int* __restrict__ gsorted,
    const float* __restrict__ hl, const float* __restrict__ hself,
    float* __restrict__ out)
{
    int gid = blockIdx.x * blockDim.x + threadIdx.x;
    int n = gid >> 4, t = gid & 15;
    if (n >= N_NODES) return;
    int2 md = gmeta[n];
    int beg = md.x, dg = md.y;
    float a0 = 0.f, a1 = 0.f;
    int i = 0;
    for (; i + 1 < dg; i += 2) {
        int sA = gsorted[beg + i];
        int sB = gsorted[beg + i + 1];
        a0 += hl[(size_t)sA * OUT_CH + t];
        a1 += hl[(size_t)sB * OUT_CH + t];
    }
    if (i < dg) a0 += hl[(size_t)gsorted[beg + i] * OUT_CH + t];
    float invd = 1.0f / (float)max(dg, 1);
    float v = fmaf(a0 + a1, invd, hself[(size_t)n * OUT_CH + t]);
    float ss = v * v;
    ss += __shfl_xor(ss, 1);
    ss += __shfl_xor(ss, 2);
    ss += __shfl_xor(ss, 4);
    ss += __shfl_xor(ss, 8);
    v *= 1.0f / fmaxf(sqrtf(ss), EPSN);
    float m = v;
    m = fmaxf(m, __shfl_xor(m, 1));
    m = fmaxf(m, __shfl_xor(m, 2));
    m = fmaxf(m, __shfl_xor(m, 4));
    m = fmaxf(m, __shfl_xor(m, 8));
    float ex = expf(v - m);
    float sum = ex;
    sum += __shfl_xor(sum, 1);
    sum += __shfl_xor(sum, 2);
    sum += __shfl_xor(sum, 4);
    sum += __shfl_xor(sum, 8);
    out[(size_t)n * OUT_CH + t] = (v - m) - logf(sum);
}

extern "C" void kernel_launch(void* const* d_in, const int* in_sizes, int n_in,
                              void* d_out, int out_size, void* d_ws, size_t ws_size,
                              hipStream_t stream) {
    const float* x   = (const float*)d_in[0];
    const int*   ei  = (const int*)d_in[1];   // [2, E] int32
    const float* W1l = (const float*)d_in[2];
    const float* b1l = (const float*)d_in[3];
    const float* W1r = (const float*)d_in[4];
    const float* W2l = (const float*)d_in[5];
    const float* b2l = (const float*)d_in[6];
    const float* W2r = (const float*)d_in[7];
    float* out = (float*)d_out;

    const int* src = ei;
    const int* dst = ei + N_EDGES;

    // workspace layout (~53 MB)
    char* p = (char*)d_ws;
    float*    xl      = (float*)p;    p += (size_t)N_NODES * HID_CH * 4;   // 12.8 MB
    float*    self1   = (float*)p;    p += (size_t)N_NODES * HID_CH * 4;   // 12.8 MB
    float*    hl      = (float*)p;    p += (size_t)N_NODES * OUT_CH * 4;   //  6.4 MB
    float*    hself   = (float*)p;    p += (size_t)N_NODES * OUT_CH * 4;   //  6.4 MB
    int2*     gmeta   = (int2*)p;     p += (size_t)N_NODES * 8;            //  0.8 MB
    int*      cnt     = (int*)p;      p += (size_t)NBUCK * CBLK * 4;       //  0.6 MB
    int*      tot     = (int*)p;      p += (size_t)NBUCK * 4;
    int*      bbase   = (int*)p;      p += (size_t)(NBUCK + 1) * 4;
    unsigned* ebuf    = (unsigned*)p; p += (size_t)N_EDGES * 4;            //  6.4 MB
    int*      gsorted = (int*)p;      p += (size_t)N_EDGES * 4;            //  6.4 MB

    k_xform1<<<(N_NODES + TNB - 1) / TNB, 256, 0, stream>>>(x, W1l, b1l, W1r, xl, self1);
    k_count<<<CBLK, 256, 0, stream>>>(dst, cnt);
    k_scanA<<<NBUCK, 64, 0, stream>>>(cnt, tot);
    k_scanB<<<1, 1024, 0, stream>>>(tot, bbase);
    k_place<<<CBLK, 256, 0, stream>>>(src, dst, cnt, bbase, ebuf);
    k_aggr1_x2<<<NBUCK, 512, 0, stream>>>(bbase, ebuf, xl, self1,
                                          W2l, b2l, W2r, hl, hself, gsorted, gmeta);
    k_aggr2_fin<<<(N_NODES * 16 + 255) / 256, 256, 0, stream>>>(gmeta, gsorted,
                                                                hl, hself, out);
}

// Round 6
// 122.524 us; speedup vs baseline: 8.1430x; 1.3789x over previous
//
#include <hip/hip_runtime.h>

#define N_NODES 100000
#define N_EDGES 1600000
#define IN_CH 50
#define HID_CH 32
#define OUT_CH 16
#define EPSN 1e-12f

#define NPB 128                                  // nodes per bucket (dst>>7)
#define NBUCK ((N_NODES + NPB - 1) / NPB)        // 782
#define EPB 8192                                 // edges per count/place block
#define CBLK ((N_EDGES + EPB - 1) / EPB)         // 196
#define LCAP 2816                                // LDS bucket capacity (mean 2048, +17 sigma)

#define KPAD 52                                  // 50 padded to multiple of 4
#define KV (KPAD / 4)                            // 13 float4 per row
#define TNB 128                                  // nodes per xform1 block
#define BSTR 35                                  // bounce tile stride (bank-spread)

__device__ __forceinline__ unsigned short f2bf(float f) {
    unsigned u = __float_as_uint(f);
    u += 0x7FFFu + ((u >> 16) & 1u);             // round-to-nearest-even
    return (unsigned short)(u >> 16);
}
__device__ __forceinline__ float blo(unsigned u) { return __uint_as_float(u << 16); }
__device__ __forceinline__ float bhi(unsigned u) { return __uint_as_float(u & 0xFFFF0000u); }

// ---------------- layer-1 transform as LDS-tiled GEMM: [N x 50] @ [50 x 64]
// outputs: xl (bf16, W1l), self1 (fp32, W1r + b1l)
__global__ __launch_bounds__(256) void k_xform1(
    const float* __restrict__ x, const float* __restrict__ W1l,
    const float* __restrict__ b1l, const float* __restrict__ W1r,
    unsigned short* __restrict__ xlb, float* __restrict__ self1)
{
    __shared__ float xs[TNB * KPAD];    // 26624 B (also reused as bounce tile)
    __shared__ float wt[64 * KPAD];     // 13312 B
    __shared__ float bsh[32];
    int tid = threadIdx.x;
    int base = blockIdx.x * TNB;

    // stage x tile (coalesced); rows past N_NODES read as 0
    for (int i = tid; i < TNB * IN_CH; i += 256) {
        int r = i / IN_CH, k = i - r * IN_CH;
        int n = base + r;
        xs[r * KPAD + k] = (n < N_NODES) ? x[(size_t)base * IN_CH + i] : 0.f;
    }
    xs[(tid >> 1) * KPAD + IN_CH + (tid & 1)] = 0.f;            // K pads
    if (tid < 128) wt[(tid >> 1) * KPAD + IN_CH + (tid & 1)] = 0.f;
    for (int i = tid; i < 64 * IN_CH; i += 256) {
        int o = i / IN_CH, k = i - o * IN_CH;
        wt[o * KPAD + k] = (o < 32) ? W1l[i] : W1r[i - 32 * IN_CH];
    }
    if (tid < 32) bsh[tid] = b1l[tid];
    __syncthreads();

    int q = tid & 7;
    int loc = tid >> 3;
    const float4* xs4 = (const float4*)xs;
    const float4* wt4 = (const float4*)wt;
    float acc[4][8] = {};
    for (int kk = 0; kk < KV; ++kk) {
        float4 w[8];
        #pragma unroll
        for (int j = 0; j < 8; ++j) w[j] = wt4[(j * 8 + q) * KV + kk];
        #pragma unroll
        for (int nn = 0; nn < 4; ++nn) {
            float4 xv = xs4[(loc + nn * 32) * KV + kk];
            #pragma unroll
            for (int j = 0; j < 8; ++j) {
                acc[nn][j] = fmaf(xv.x, w[j].x, acc[nn][j]);
                acc[nn][j] = fmaf(xv.y, w[j].y, acc[nn][j]);
                acc[nn][j] = fmaf(xv.z, w[j].z, acc[nn][j]);
                acc[nn][j] = fmaf(xv.w, w[j].w, acc[nn][j]);
            }
        }
    }
    __syncthreads();   // all xs reads done; reuse as bounce
    float* bounce = xs;
    #pragma unroll
    for (int nn = 0; nn < 4; ++nn)
        #pragma unroll
        for (int j = 0; j < 4; ++j)
            bounce[(loc + nn * 32) * BSTR + j * 8 + q] = acc[nn][j];
    __syncthreads();
    for (int i = tid; i < TNB * 16; i += 256) {   // pack xl as bf16x2
        int node = i >> 4, pr = i & 15;
        int n = base + node;
        if (n < N_NODES) {
            ushort2 o;
            o.x = f2bf(bounce[node * BSTR + 2 * pr]);
            o.y = f2bf(bounce[node * BSTR + 2 * pr + 1]);
            ((ushort2*)xlb)[(size_t)n * 16 + pr] = o;
        }
    }
    __syncthreads();
    #pragma unroll
    for (int nn = 0; nn < 4; ++nn)
        #pragma unroll
        for (int j = 0; j < 4; ++j)
            bounce[(loc + nn * 32) * BSTR + j * 8 + q] = acc[nn][j + 4] + bsh[j * 8 + q];
    __syncthreads();
    for (int i = tid; i < TNB * 8; i += 256) {    // self1 as float4
        int node = i >> 3, f = i & 7;
        int n = base + node;
        if (n < N_NODES) {
            float4 v;
            v.x = bounce[node * BSTR + f * 4 + 0];
            v.y = bounce[node * BSTR + f * 4 + 1];
            v.z = bounce[node * BSTR + f * 4 + 2];
            v.w = bounce[node * BSTR + f * 4 + 3];
            ((float4*)self1)[(size_t)n * 8 + f] = v;
        }
    }
}

// ---------------- per-block privatized bucket histogram (no global atomics)
__global__ __launch_bounds__(256) void k_count(
    const int* __restrict__ dst, int* __restrict__ cnt)
{
    __shared__ int hist[NBUCK];
    int tid = threadIdx.x;
    for (int i = tid; i < NBUCK; i += 256) hist[i] = 0;
    __syncthreads();
    int base = blockIdx.x * EPB;
    for (int i = tid; i < EPB; i += 256) {
        int e = base + i;
        if (e < N_EDGES) atomicAdd(&hist[dst[e] >> 7], 1);
    }
    __syncthreads();
    for (int b = tid; b < NBUCK; b += 256) cnt[b * CBLK + blockIdx.x] = hist[b];
}

// ---------------- scan each bucket's per-block counts (one wave per bucket)
__global__ __launch_bounds__(64) void k_scanA(
    int* __restrict__ cnt, int* __restrict__ tot)
{
    int b = blockIdx.x, lane = threadIdx.x;
    int carry = 0;
    for (int c = 0; c < CBLK; c += 64) {
        int idx = c + lane;
        int v = (idx < CBLK) ? cnt[b * CBLK + idx] : 0;
        int s = v;
        #pragma unroll
        for (int off = 1; off < 64; off <<= 1) {
            int t = __shfl_up(s, off);
            if (lane >= off) s += t;
        }
        if (idx < CBLK) cnt[b * CBLK + idx] = carry + s - v;  // exclusive within bucket
        carry += __shfl(s, 63);
    }
    if (lane == 0) tot[b] = carry;
}

// ---------------- scan bucket totals (single block)
__global__ __launch_bounds__(1024) void k_scanB(
    const int* __restrict__ tot, int* __restrict__ bbase)
{
    __shared__ int buf[1024];
    int tid = threadIdx.x;
    int v = (tid < NBUCK) ? tot[tid] : 0;
    buf[tid] = v;
    __syncthreads();
    for (int off = 1; off < 1024; off <<= 1) {
        int t = (tid >= off) ? buf[tid - off] : 0;
        __syncthreads();
        buf[tid] += t;
        __syncthreads();
    }
    if (tid < NBUCK) bbase[tid] = buf[tid] - v;
    if (tid == NBUCK - 1) bbase[NBUCK] = buf[tid];
}

// ---------------- place edges at exact packed positions (LDS rank only)
__global__ __launch_bounds__(256) void k_place(
    const int* __restrict__ src, const int* __restrict__ dst,
    const int* __restrict__ cnt, const int* __restrict__ bbase,
    unsigned* __restrict__ ebuf)
{
    __shared__ int hbase[NBUCK];
    __shared__ int hrank[NBUCK];
    int tid = threadIdx.x;
    for (int b = tid; b < NBUCK; b += 256) {
        hbase[b] = bbase[b] + cnt[b * CBLK + blockIdx.x];
        hrank[b] = 0;
    }
    __syncthreads();
    int base = blockIdx.x * EPB;
    for (int i = tid; i < EPB; i += 256) {
        int e = base + i;
        if (e < N_EDGES) {
            int d = dst[e];
            int bb = d >> 7;
            int r = atomicAdd(&hrank[bb], 1);
            ebuf[hbase[bb] + r] = ((unsigned)(d & (NPB - 1)) << 24) | (unsigned)src[e];
        }
    }
}

// ---------------- per-bucket: LDS counting-sort by node, 4-lane bf16 gather,
//                  finalize layer 1, fused layer-2 transform via shfl
__global__ __launch_bounds__(512) void k_aggr1_x2(
    const int* __restrict__ bbase, const unsigned* __restrict__ ebuf,
    const unsigned short* __restrict__ xlb, const float* __restrict__ self1,
    const float* __restrict__ W2l, const float* __restrict__ b2l,
    const float* __restrict__ W2r,
    unsigned short* __restrict__ hlb, float* __restrict__ hself,
    int* __restrict__ gsorted, int2* __restrict__ gmeta)
{
    __shared__ unsigned ent[LCAP];
    __shared__ int slist[LCAP];
    __shared__ int hcnt[NPB];
    __shared__ int hoff[NPB + 1];
    __shared__ float w2[2 * OUT_CH * 33];
    __shared__ float b2s[OUT_CH];

    int tid = threadIdx.x;
    int b = blockIdx.x;
    for (int i = tid; i < OUT_CH * HID_CH; i += 512) {
        int o = i >> 5, k = i & 31;
        w2[o * 33 + k] = W2l[i];
        w2[(OUT_CH + o) * 33 + k] = W2r[i];
    }
    if (tid < OUT_CH) b2s[tid] = b2l[tid];
    if (tid < NPB) hcnt[tid] = 0;
    __syncthreads();

    int beg = bbase[b];
    int cnt = min(bbase[b + 1] - beg, LCAP);
    for (int i = tid; i < cnt; i += 512) {
        unsigned e = ebuf[beg + i];
        ent[i] = e;
        atomicAdd(&hcnt[e >> 24], 1);
    }
    __syncthreads();
    if (tid < 64) {   // scan 128 node counts in one wave
        int v0 = hcnt[2 * tid], v1 = hcnt[2 * tid + 1];
        int s = v0 + v1;
        #pragma unroll
        for (int off = 1; off < 64; off <<= 1) {
            int t = __shfl_up(s, off);
            if (tid >= off) s += t;
        }
        int exc = s - v0 - v1;
        hoff[2 * tid] = exc;
        hoff[2 * tid + 1] = exc + v0;
        if (tid == 63) hoff[NPB] = s;
    }
    __syncthreads();
    if (tid < NPB) hcnt[tid] = 0;
    __syncthreads();
    for (int i = tid; i < cnt; i += 512) {
        unsigned e = ent[i];
        int loc = e >> 24;
        int r = atomicAdd(&hcnt[loc], 1);
        slist[hoff[loc] + r] = (int)(e & 0xFFFFFFu);
    }
    __syncthreads();
    for (int i = tid; i < cnt; i += 512) gsorted[beg + i] = slist[i];

    // ---- gather: 4 lanes per node, 16B bf16x8 loads, 2-way unroll
    int q = tid & 3;               // lane's channel block: ch q*8..q*8+7
    int loc = tid >> 2;            // node 0..127 (one pass)
    int wl = tid & 63;
    int n = b * NPB + loc;
    if (n >= N_NODES) return;
    int s0 = hoff[loc];
    int dg = hoff[loc + 1] - s0;
    float acc[8] = {};
    int i = 0;
    for (; i + 1 < dg; i += 2) {
        int sA = slist[s0 + i];
        int sB = slist[s0 + i + 1];
        uint4 uA = *((const uint4*)(xlb + (size_t)sA * 32) + q);
        uint4 uB = *((const uint4*)(xlb + (size_t)sB * 32) + q);
        acc[0] += blo(uA.x); acc[1] += bhi(uA.x);
        acc[2] += blo(uA.y); acc[3] += bhi(uA.y);
        acc[4] += blo(uA.z); acc[5] += bhi(uA.z);
        acc[6] += blo(uA.w); acc[7] += bhi(uA.w);
        acc[0] += blo(uB.x); acc[1] += bhi(uB.x);
        acc[2] += blo(uB.y); acc[3] += bhi(uB.y);
        acc[4] += blo(uB.z); acc[5] += bhi(uB.z);
        acc[6] += blo(uB.w); acc[7] += bhi(uB.w);
    }
    if (i < dg) {
        int sA = slist[s0 + i];
        uint4 uA = *((const uint4*)(xlb + (size_t)sA * 32) + q);
        acc[0] += blo(uA.x); acc[1] += bhi(uA.x);
        acc[2] += blo(uA.y); acc[3] += bhi(uA.y);
        acc[4] += blo(uA.z); acc[5] += bhi(uA.z);
        acc[6] += blo(uA.w); acc[7] += bhi(uA.w);
    }
    float invd = 1.0f / (float)max(dg, 1);
    float4 sf0 = ((const float4*)self1)[(size_t)n * 8 + q * 2];
    float4 sf1 = ((const float4*)self1)[(size_t)n * 8 + q * 2 + 1];
    float h[8];
    h[0] = fmaf(acc[0], invd, sf0.x); h[1] = fmaf(acc[1], invd, sf0.y);
    h[2] = fmaf(acc[2], invd, sf0.z); h[3] = fmaf(acc[3], invd, sf0.w);
    h[4] = fmaf(acc[4], invd, sf1.x); h[5] = fmaf(acc[5], invd, sf1.y);
    h[6] = fmaf(acc[6], invd, sf1.z); h[7] = fmaf(acc[7], invd, sf1.w);
    float ss = 0.f;
    #pragma unroll
    for (int j = 0; j < 8; ++j) ss += h[j] * h[j];
    ss += __shfl_xor(ss, 1);
    ss += __shfl_xor(ss, 2);
    float sc = 1.0f / fmaxf(sqrtf(ss), EPSN);
    #pragma unroll
    for (int j = 0; j < 8; ++j) h[j] = fmaxf(h[j] * sc, 0.f);

    // fused xform2: lane q computes out channels q*4+m via 32 static shfls
    float aL[4] = {}, aR[4] = {};
    int gbase = wl & 60;
    #pragma unroll
    for (int k = 0; k < HID_CH; ++k) {
        float hv = __shfl(h[k & 7], gbase | (k >> 3));
        #pragma unroll
        for (int m = 0; m < 4; ++m) {
            aL[m] = fmaf(hv, w2[(q * 4 + m) * 33 + k], aL[m]);
            aR[m] = fmaf(hv, w2[(OUT_CH + q * 4 + m) * 33 + k], aR[m]);
        }
    }
    uint2 hp;
    hp.x = (unsigned)f2bf(aL[0]) | ((unsigned)f2bf(aL[1]) << 16);
    hp.y = (unsigned)f2bf(aL[2]) | ((unsigned)f2bf(aL[3]) << 16);
    ((uint2*)hlb)[(size_t)n * 4 + q] = hp;
    float4 hs;
    hs.x = aR[0] + b2s[q * 4 + 0];
    hs.y = aR[1] + b2s[q * 4 + 1];
    hs.z = aR[2] + b2s[q * 4 + 2];
    hs.w = aR[3] + b2s[q * 4 + 3];
    ((float4*)hself)[(size_t)n * 4 + q] = hs;
    if (q == 0) gmeta[n] = make_int2(beg + s0, dg);
}

// ---------------- layer-2: 4-lane bf16 gather + mean + self + L2norm + log_softmax
__global__ __launch_bounds__(256) void k_aggr2_fin(
    const int2* __restrict__ gmeta, const int* __restrict__ gsorted,
    const unsigned short* __restrict__ hlb, const float* __restrict__ hself,
    float* __restrict__ out)
{
    int gid = blockIdx.x * blockDim.x + threadIdx.x;
    int n = gid >> 2, q = gid & 3;        // 4 lanes/node, ch q*4..q*4+3
    if (n >= N_NODES) return;
    int2 md = gmeta[n];
    int beg = md.x, dg = md.y;
    float a[4] = {};
    int i = 0;
    for (; i + 1 < dg; i += 2) {
        int sA = gsorted[beg + i];
        int sB = gsorted[beg + i + 1];
        uint2 uA = *((const uint2*)(hlb + (size_t)sA * 16) + q);
        uint2 uB = *((const uint2*)(hlb + (size_t)sB * 16) + q);
        a[0] += blo(uA.x); a[1] += bhi(uA.x);
        a[2] += blo(uA.y); a[3] += bhi(uA.y);
        a[0] += blo(uB.x); a[1] += bhi(uB.x);
        a[2] += blo(uB.y); a[3] += bhi(uB.y);
    }
    if (i < dg) {
        int sA = gsorted[beg + i];
        uint2 uA = *((const uint2*)(hlb + (size_t)sA * 16) + q);
        a[0] += blo(uA.x); a[1] += bhi(uA.x);
        a[2] += blo(uA.y); a[3] += bhi(uA.y);
    }
    float invd = 1.0f / (float)max(dg, 1);
    float4 hs = ((const float4*)hself)[(size_t)n * 4 + q];
    float v[4];
    v[0] = fmaf(a[0], invd, hs.x); v[1] = fmaf(a[1], invd, hs.y);
    v[2] = fmaf(a[2], invd, hs.z); v[3] = fmaf(a[3], invd, hs.w);
    float ss = v[0]*v[0] + v[1]*v[1] + v[2]*v[2] + v[3]*v[3];
    ss += __shfl_xor(ss, 1);
    ss += __shfl_xor(ss, 2);
    float sc = 1.0f / fmaxf(sqrtf(ss), EPSN);
    #pragma unroll
    for (int m = 0; m < 4; ++m) v[m] *= sc;
    float mx = fmaxf(fmaxf(v[0], v[1]), fmaxf(v[2], v[3]));
    mx = fmaxf(mx, __shfl_xor(mx, 1));
    mx = fmaxf(mx, __shfl_xor(mx, 2));
    float sum = expf(v[0]-mx) + expf(v[1]-mx) + expf(v[2]-mx) + expf(v[3]-mx);
    sum += __shfl_xor(sum, 1);
    sum += __shfl_xor(sum, 2);
    float lse = mx + logf(sum);
    float4 o;
    o.x = v[0] - lse; o.y = v[1] - lse; o.z = v[2] - lse; o.w = v[3] - lse;
    ((float4*)out)[(size_t)n * 4 + q] = o;
}

extern "C" void kernel_launch(void* const* d_in, const int* in_sizes, int n_in,
                              void* d_out, int out_size, void* d_ws, size_t ws_size,
                              hipStream_t stream) {
    const float* x   = (const float*)d_in[0];
    const int*   ei  = (const int*)d_in[1];   // [2, E] int32
    const float* W1l = (const float*)d_in[2];
    const float* b1l = (const float*)d_in[3];
    const float* W1r = (const float*)d_in[4];
    const float* W2l = (const float*)d_in[5];
    const float* b2l = (const float*)d_in[6];
    const float* W2r = (const float*)d_in[7];
    float* out = (float*)d_out;

    const int* src = ei;
    const int* dst = ei + N_EDGES;

    // workspace layout (~43 MB)
    char* p = (char*)d_ws;
    unsigned short* xlb   = (unsigned short*)p; p += (size_t)N_NODES * HID_CH * 2;  // 6.4 MB, 16B-aligned
    float*          self1 = (float*)p;          p += (size_t)N_NODES * HID_CH * 4;  // 12.8 MB
    unsigned short* hlb   = (unsigned short*)p; p += (size_t)N_NODES * OUT_CH * 2;  // 3.2 MB
    float*          hself = (float*)p;          p += (size_t)N_NODES * OUT_CH * 4;  // 6.4 MB
    int2*           gmeta = (int2*)p;           p += (size_t)N_NODES * 8;           // 0.8 MB
    int*            cnt   = (int*)p;            p += (size_t)NBUCK * CBLK * 4;      // 0.6 MB
    int*            tot   = (int*)p;            p += (size_t)NBUCK * 4;
    int*            bbase = (int*)p;            p += (size_t)(NBUCK + 1) * 4;
    unsigned*       ebuf  = (unsigned*)p;       p += (size_t)N_EDGES * 4;           // 6.4 MB
    int*            gsorted = (int*)p;          p += (size_t)N_EDGES * 4;           // 6.4 MB

    k_xform1<<<(N_NODES + TNB - 1) / TNB, 256, 0, stream>>>(x, W1l, b1l, W1r, xlb, self1);
    k_count<<<CBLK, 256, 0, stream>>>(dst, cnt);
    k_scanA<<<NBUCK, 64, 0, stream>>>(cnt, tot);
    k_scanB<<<1, 1024, 0, stream>>>(tot, bbase);
    k_place<<<CBLK, 256, 0, stream>>>(src, dst, cnt, bbase, ebuf);
    k_aggr1_x2<<<NBUCK, 512, 0, stream>>>(bbase, ebuf, xlb, self1,
                                          W2l, b2l, W2r, hlb, hself, gsorted, gmeta);
    k_aggr2_fin<<<(N_NODES * 4 + 255) / 256, 256, 0, stream>>>(gmeta, gsorted,
                                                               hlb, hself, out);
}